// Round 1
// baseline (269.287 us; speedup 1.0000x reference)
//
#include <hip/hip_runtime.h>
#include <stdint.h>

// ---------------------------------------------------------------------------
// CustomGPT2MultiHeadAttention: B=4, S=1024, SI=512, D=1024, H=16, Dh=64
// Pipeline (all bf16 MFMA, fp32 accum):
//   1) mask_pack:  int32 mask -> 1 bit per entry (786 KB, L2-resident)
//   2) cast_hi:    hidden+image fp32 -> bf16
//   3) cast_w6:    6 weight matrices fp32 -> bf16 (contiguous: wq wk wv uk uv wo)
//   4) gemm<4>:    [4096,1024] x [3072,1024]^T -> Q(token-major), K(concat rows),
//                  V written TRANSPOSED (Vt[b][d_model][1536]) for K-contiguous PV
//   5) gemm<5>:    image -> K rows 1024..1535, Vt cols 1024..1535
//   6) attn:       flash-style online softmax, 64 q/block, KT=32
//   7) gemm<2>:    attn_out x w_o^T -> fp32 d_out
// Workspace: ~57 MB (see kernel_launch offsets).
// ---------------------------------------------------------------------------

typedef unsigned short u16;
typedef short bf16x8v __attribute__((ext_vector_type(8)));
typedef float f32x4 __attribute__((ext_vector_type(4)));

__device__ __forceinline__ u16 f2bf(float f) {
  union { float f; uint32_t u; } x; x.f = f;
  uint32_t r = x.u + 0x7FFFu + ((x.u >> 16) & 1u);   // round-to-nearest-even
  return (u16)(r >> 16);
}

__device__ __forceinline__ void gl_lds16(const u16* g, u16* l) {
  __builtin_amdgcn_global_load_lds((const __attribute__((address_space(1))) unsigned int*)g,
                                   (__attribute__((address_space(3))) unsigned int*)l,
                                   16, 0, 0);
}

// ---------------------------------------------------------------------------
// 1) mask bit-pack: 6,291,456 int32 -> 196,608 uint32 words
__global__ __launch_bounds__(256) void mask_pack(const int* __restrict__ m,
                                                 uint32_t* __restrict__ Mw) {
  int gtid = blockIdx.x * 256 + threadIdx.x;
  int lane = threadIdx.x & 63;
  unsigned long long bal = __ballot(m[gtid] != 0);
  if ((lane & 31) == 0)
    Mw[gtid >> 5] = (uint32_t)((lane == 32) ? (bal >> 32) : bal);
}

// ---------------------------------------------------------------------------
// 2) cast hidden (1,048,576 float4) + image (524,288 float4) -> bf16
__global__ __launch_bounds__(256) void cast_hi(const float4* __restrict__ hs,
                                               const float4* __restrict__ im,
                                               u16* __restrict__ Hb, u16* __restrict__ Ib) {
  int i = blockIdx.x * 256 + threadIdx.x;   // < 1,572,864
  float4 v; u16* d;
  if (i < 1048576) { v = hs[i];            d = Hb + (size_t)i * 4; }
  else             { v = im[i - 1048576];  d = Ib + (size_t)(i - 1048576) * 4; }
  ushort4 o; o.x = f2bf(v.x); o.y = f2bf(v.y); o.z = f2bf(v.z); o.w = f2bf(v.w);
  *(ushort4*)d = o;
}

// 3) cast 6 weights, each 262,144 float4 units, into one contiguous buffer
__global__ __launch_bounds__(256) void cast_w6(const float4* __restrict__ w0, const float4* __restrict__ w1,
                                               const float4* __restrict__ w2, const float4* __restrict__ w3,
                                               const float4* __restrict__ w4, const float4* __restrict__ w5,
                                               u16* __restrict__ Wb) {
  int i = blockIdx.x * 256 + threadIdx.x;   // < 1,572,864
  int w = i >> 18, off = i & 262143;
  const float4* s;
  switch (w) {
    case 0: s = w0; break; case 1: s = w1; break; case 2: s = w2; break;
    case 3: s = w3; break; case 4: s = w4; break; default: s = w5; break;
  }
  float4 v = s[off];
  ushort4 o; o.x = f2bf(v.x); o.y = f2bf(v.y); o.z = f2bf(v.z); o.w = f2bf(v.w);
  *(ushort4*)(Wb + ((size_t)w << 20) + (size_t)off * 4) = o;
}

// ---------------------------------------------------------------------------
// GEMM: C[m,n] = sum_k A[m,k] * B[n,k]   (A: [M,K] row-major, B: [N,K] row-major)
// Tile 128(M) x 64(N), BK=32, 256 threads = 4 waves (2x2), wave owns 64x32.
// MODE 2: fp32 direct to Cout.
// MODE 4: self QKV  (N=3072): gn<1024 -> Q ; <2048 -> K concat rows ; else Vt scatter
// MODE 5: image KV  (N=2048): gn<1024 -> K rows+1024 ; else Vt cols+1024
template<int MODE>
__global__ __launch_bounds__(256) void gemm_bt(const u16* __restrict__ A, const u16* __restrict__ Bm,
                                               void* __restrict__ Cout, int M, int N, int K,
                                               u16* __restrict__ Qd, u16* __restrict__ Kd,
                                               u16* __restrict__ Vd)
{
  __shared__ __align__(16) u16 As[128 * 32];   // 8 KB
  __shared__ __align__(16) u16 Bs[64 * 32];    // 4 KB
  const int tid  = threadIdx.x;
  const int lane = tid & 63, wave = tid >> 6;
  const int wr = wave >> 1, wc = wave & 1;
  const int g = lane >> 4, c = lane & 15;
  const int bm = blockIdx.y * 128;
  const int bn = blockIdx.x * 64;

  f32x4 zf = {0.f, 0.f, 0.f, 0.f};
  f32x4 acc[4][2];
  #pragma unroll
  for (int mi = 0; mi < 4; ++mi)
    #pragma unroll
    for (int ni = 0; ni < 2; ++ni) acc[mi][ni] = zf;

  const int srow = tid >> 2;            // 0..63
  const int sch  = (tid & 3) * 8;       // k-chunk within row

  for (int k0 = 0; k0 < K; k0 += 32) {
    gl_lds16(A  + (size_t)(bm + srow) * K + k0 + sch,      &As[tid * 8]);
    gl_lds16(A  + (size_t)(bm + 64 + srow) * K + k0 + sch, &As[2048 + tid * 8]);
    gl_lds16(Bm + (size_t)(bn + srow) * K + k0 + sch,      &Bs[tid * 8]);
    __syncthreads();
    bf16x8v af[4], bf[2];
    #pragma unroll
    for (int mi = 0; mi < 4; ++mi) af[mi] = *(const bf16x8v*)&As[(wr * 64 + mi * 16 + c) * 32 + g * 8];
    #pragma unroll
    for (int ni = 0; ni < 2; ++ni) bf[ni] = *(const bf16x8v*)&Bs[(wc * 32 + ni * 16 + c) * 32 + g * 8];
    #pragma unroll
    for (int mi = 0; mi < 4; ++mi)
      #pragma unroll
      for (int ni = 0; ni < 2; ++ni)
        acc[mi][ni] = __builtin_amdgcn_mfma_f32_16x16x32_bf16(af[mi], bf[ni], acc[mi][ni], 0, 0, 0);
    __syncthreads();
  }

  // epilogue: C row = 4*g + j, col = c (verified m89 C/D layout)
  #pragma unroll
  for (int mi = 0; mi < 4; ++mi) {
    #pragma unroll
    for (int ni = 0; ni < 2; ++ni) {
      #pragma unroll
      for (int j = 0; j < 4; ++j) {
        int gm = bm + wr * 64 + mi * 16 + 4 * g + j;
        int gn = bn + wc * 32 + ni * 16 + c;
        float v = acc[mi][ni][j];
        if (MODE == 2) {
          ((float*)Cout)[(size_t)gm * N + gn] = v;
        } else if (MODE == 4) {
          int b_ = gm >> 10, s_ = gm & 1023;
          if (gn < 1024)      Qd[(size_t)gm * 1024 + gn] = f2bf(v);
          else if (gn < 2048) Kd[(size_t)(b_ * 1536 + s_) * 1024 + (gn - 1024)] = f2bf(v);
          else                Vd[(size_t)(b_ * 1024 + (gn - 2048)) * 1536 + s_] = f2bf(v);
        } else if (MODE == 5) {
          int b_ = gm >> 9, s_ = gm & 511;
          if (gn < 1024) Kd[(size_t)(b_ * 1536 + 1024 + s_) * 1024 + gn] = f2bf(v);
          else           Vd[(size_t)(b_ * 1024 + (gn - 1024)) * 1536 + 1024 + s_] = f2bf(v);
        }
      }
    }
  }
}

// ---------------------------------------------------------------------------
// 6) flash attention: grid (S/64, H, B), 256 threads = 4 waves, wave = 16 q rows.
//    K tile [32][64] (stride 72 elems), Vt tile [64][32] (stride 40), KT=32.
__global__ __launch_bounds__(256) void attn_kernel(const u16* __restrict__ Q, const u16* __restrict__ Kc,
                                                   const u16* __restrict__ Vt,
                                                   const uint32_t* __restrict__ Mw,
                                                   u16* __restrict__ AO)
{
  const int b = blockIdx.z, h = blockIdx.y;
  const int q0 = blockIdx.x * 64;
  const int tid = threadIdx.x, lane = tid & 63, wave = tid >> 6;
  const int g = lane >> 4, c = lane & 15;
  const int qw = q0 + wave * 16;

  __shared__ __align__(16) u16 Ks[32 * 72];       // 4.5 KB, padded stride
  __shared__ __align__(16) u16 Vs[64 * 40];       // 5.0 KB
  __shared__ __align__(16) u16 Ps[4][16 * 40];    // 5.0 KB, per-wave P tile
  __shared__ uint32_t Ms[64];

  // Q fragments: row = qw + c, k-chunks d = {0..31, 32..63}
  bf16x8v qf0, qf1;
  {
    const u16* qp = Q + (size_t)(b * 1024 + qw + c) * 1024 + h * 64 + g * 8;
    qf0 = *(const bf16x8v*)qp;
    qf1 = *(const bf16x8v*)(qp + 32);
  }
  f32x4 zf = {0.f, 0.f, 0.f, 0.f};
  f32x4 O[4];
  float m[4], l[4];
  #pragma unroll
  for (int j = 0; j < 4; ++j) { O[j] = zf; m[j] = -1e9f; l[j] = 0.f; }

  const int krow = tid >> 3, kch = (tid & 7) * 8;   // K staging: 32 rows x 64 d
  const int vrow = tid >> 2, vch = (tid & 3) * 8;   // V staging: 64 d x 32 l
  const u16* Kbase = Kc + (size_t)(b * 1536) * 1024 + h * 64;
  const u16* Vbase = Vt + (size_t)(b * 1024 + h * 64) * 1536;

  for (int kt = 0; kt < 48; ++kt) {
    const int l0 = kt * 32;
    bf16x8v kv = *(const bf16x8v*)(Kbase + (size_t)(l0 + krow) * 1024 + kch);
    bf16x8v vv = *(const bf16x8v*)(Vbase + (size_t)vrow * 1536 + l0 + vch);
    *(bf16x8v*)&Ks[krow * 72 + kch] = kv;
    *(bf16x8v*)&Vs[vrow * 40 + vch] = vv;
    if (tid < 64) Ms[tid] = Mw[(size_t)(b * 1024 + q0 + tid) * 48 + kt];
    __syncthreads();

    // S = Q K^T : C rows = q (4g+j), cols = k-local (nt*16+c)
    f32x4 s[2];
    #pragma unroll
    for (int nt = 0; nt < 2; ++nt) {
      f32x4 z = zf;
      bf16x8v kf0 = *(const bf16x8v*)&Ks[(nt * 16 + c) * 72 + g * 8];
      bf16x8v kf1 = *(const bf16x8v*)&Ks[(nt * 16 + c) * 72 + 32 + g * 8];
      z = __builtin_amdgcn_mfma_f32_16x16x32_bf16(qf0, kf0, z, 0, 0, 0);
      z = __builtin_amdgcn_mfma_f32_16x16x32_bf16(qf1, kf1, z, 0, 0, 0);
      s[nt] = z;
    }

    // online softmax (rows 4g+j; reduce over 16 lanes of the g-group x 2 col-tiles)
    float p0a[4], p1a[4], scj[4];
    #pragma unroll
    for (int j = 0; j < 4; ++j) {
      uint32_t mw = Ms[wave * 16 + 4 * g + j];
      float s0 = s[0][j] * 0.125f;
      float s1 = s[1][j] * 0.125f;
      s0 = ((mw >> c) & 1u)        ? s0 : -1e9f;
      s1 = ((mw >> (16 + c)) & 1u) ? s1 : -1e9f;
      float rm = fmaxf(s0, s1);
      rm = fmaxf(rm, __shfl_xor(rm, 1));
      rm = fmaxf(rm, __shfl_xor(rm, 2));
      rm = fmaxf(rm, __shfl_xor(rm, 4));
      rm = fmaxf(rm, __shfl_xor(rm, 8));
      float mn = fmaxf(m[j], rm);
      float sc = __expf(m[j] - mn);
      m[j] = mn;
      float p0 = __expf(s0 - mn);
      float p1 = __expf(s1 - mn);
      float r = p0 + p1;
      r += __shfl_xor(r, 1);
      r += __shfl_xor(r, 2);
      r += __shfl_xor(r, 4);
      r += __shfl_xor(r, 8);
      l[j] = l[j] * sc + r;
      scj[j] = sc;
      p0a[j] = p0; p1a[j] = p1;
    }
    #pragma unroll
    for (int dt = 0; dt < 4; ++dt)
      #pragma unroll
      for (int j = 0; j < 4; ++j) O[dt][j] *= scj[j];

    // P -> LDS (per-wave), reload as MFMA A-fragment
    u16* pw = &Ps[wave][0];
    #pragma unroll
    for (int j = 0; j < 4; ++j) {
      pw[(4 * g + j) * 40 + c]      = f2bf(p0a[j]);
      pw[(4 * g + j) * 40 + 16 + c] = f2bf(p1a[j]);
    }
    bf16x8v pa = *(const bf16x8v*)&pw[c * 40 + g * 8];
    #pragma unroll
    for (int dt = 0; dt < 4; ++dt) {
      bf16x8v vf = *(const bf16x8v*)&Vs[(dt * 16 + c) * 40 + g * 8];
      O[dt] = __builtin_amdgcn_mfma_f32_16x16x32_bf16(pa, vf, O[dt], 0, 0, 0);
    }
    __syncthreads();
  }

  #pragma unroll
  for (int j = 0; j < 4; ++j) {
    float inv = 1.f / l[j];
    size_t ro = (size_t)(b * 1024 + qw + 4 * g + j) * 1024 + h * 64;
    #pragma unroll
    for (int dt = 0; dt < 4; ++dt)
      AO[ro + dt * 16 + c] = f2bf(O[dt][j] * inv);
  }
}

// ---------------------------------------------------------------------------
extern "C" void kernel_launch(void* const* d_in, const int* in_sizes, int n_in,
                              void* d_out, int out_size, void* d_ws, size_t ws_size,
                              hipStream_t stream) {
  (void)in_sizes; (void)n_in; (void)out_size; (void)ws_size;
  const float* hs = (const float*)d_in[0];
  const float* im = (const float*)d_in[1];
  const int*   mk = (const int*)d_in[2];
  const float* wq = (const float*)d_in[3];
  const float* wk = (const float*)d_in[4];
  const float* wv = (const float*)d_in[5];
  const float* uk = (const float*)d_in[6];
  const float* uv = (const float*)d_in[7];
  const float* wo = (const float*)d_in[8];

  char* ws = (char*)d_ws;
  u16* Hb  = (u16*)(ws + 0);          //  8,388,608 B  hidden bf16; reused as attn-out
  u16* Ib  = (u16*)(ws + 8388608);    //  4,194,304 B  image bf16
  u16* Wb  = (u16*)(ws + 12582912);   // 12,582,912 B  weights bf16 (wq wk wv uk uv wo)
  u16* Qb  = (u16*)(ws + 25165824);   //  8,388,608 B  Q token-major [4096][1024]
  u16* Kb  = (u16*)(ws + 33554432);   // 12,582,912 B  K concat [4][1536][1024]
  u16* Vtb = (u16*)(ws + 46137344);   // 12,582,912 B  V transposed [4][1024][1536]
  uint32_t* Mw = (uint32_t*)(ws + 58720256); // 786,432 B packed mask
  // total ws: 59,506,688 B

  mask_pack<<<24576, 256, 0, stream>>>(mk, Mw);
  cast_hi<<<6144, 256, 0, stream>>>((const float4*)hs, (const float4*)im, Hb, Ib);
  cast_w6<<<6144, 256, 0, stream>>>((const float4*)wq, (const float4*)wk, (const float4*)wv,
                                    (const float4*)uk, (const float4*)uv, (const float4*)wo, Wb);
  gemm_bt<4><<<dim3(48, 32), 256, 0, stream>>>(Hb, Wb, nullptr, 4096, 3072, 1024, Qb, Kb, Vtb);
  gemm_bt<5><<<dim3(32, 16), 256, 0, stream>>>(Ib, Wb + 3 * 1048576, nullptr, 2048, 2048, 1024,
                                               nullptr, Kb, Vtb);
  attn_kernel<<<dim3(16, 16, 4), 256, 0, stream>>>(Qb, Kb, Vtb, Mw, Hb);
  gemm_bt<2><<<dim3(16, 32), 256, 0, stream>>>(Hb, Wb + 5 * 1048576, d_out, 4096, 1024, 1024,
                                               nullptr, nullptr, nullptr);
}

// Round 2
// 196.283 us; speedup vs baseline: 1.3719x; 1.3719x over previous
//
#include <hip/hip_runtime.h>
#include <stdint.h>

// ---------------------------------------------------------------------------
// CustomGPT2MultiHeadAttention: B=4, S=1024, SI=512, D=1024, H=16, Dh=64
// Round 2: swapped-QK^T in-register softmax attention (KVBLK=64, exp2 domain,
// cvt_pk_bf16, XOR-swizzled global_load_lds staging) + m97-shape GEMM
// (128x128 tile, BK=64, swizzled gl_lds staging).
// ---------------------------------------------------------------------------

typedef unsigned short u16;
typedef short bf16x8v __attribute__((ext_vector_type(8)));
typedef float f32x4 __attribute__((ext_vector_type(4)));

__device__ __forceinline__ u16 f2bf(float f) {
  union { float f; uint32_t u; } x; x.f = f;
  uint32_t r = x.u + 0x7FFFu + ((x.u >> 16) & 1u);   // round-to-nearest-even
  return (u16)(r >> 16);
}

// v_cvt_pk_bf16_f32: D[15:0]=bf16(a), D[31:16]=bf16(b), RNE
__device__ __forceinline__ uint32_t cvtpk(float a, float b) {
  uint32_t r;
  asm("v_cvt_pk_bf16_f32 %0, %1, %2" : "=v"(r) : "v"(a), "v"(b));
  return r;
}

__device__ __forceinline__ void gl_lds16(const u16* g, u16* l) {
  __builtin_amdgcn_global_load_lds((const __attribute__((address_space(1))) unsigned int*)g,
                                   (__attribute__((address_space(3))) unsigned int*)l,
                                   16, 0, 0);
}

// ---------------------------------------------------------------------------
// 1) mask bit-pack: 6,291,456 int32 -> 196,608 uint32 words
__global__ __launch_bounds__(256) void mask_pack(const int* __restrict__ m,
                                                 uint32_t* __restrict__ Mw) {
  int gtid = blockIdx.x * 256 + threadIdx.x;
  int lane = threadIdx.x & 63;
  unsigned long long bal = __ballot(m[gtid] != 0);
  if ((lane & 31) == 0)
    Mw[gtid >> 5] = (uint32_t)((lane == 32) ? (bal >> 32) : bal);
}

// ---------------------------------------------------------------------------
// 2) cast hidden (1,048,576 float4) + image (524,288 float4) -> bf16
__global__ __launch_bounds__(256) void cast_hi(const float4* __restrict__ hs,
                                               const float4* __restrict__ im,
                                               u16* __restrict__ Hb, u16* __restrict__ Ib) {
  int i = blockIdx.x * 256 + threadIdx.x;   // < 1,572,864
  float4 v; u16* d;
  if (i < 1048576) { v = hs[i];            d = Hb + (size_t)i * 4; }
  else             { v = im[i - 1048576];  d = Ib + (size_t)(i - 1048576) * 4; }
  ushort4 o; o.x = f2bf(v.x); o.y = f2bf(v.y); o.z = f2bf(v.z); o.w = f2bf(v.w);
  *(ushort4*)d = o;
}

// 3) cast 6 weights into one contiguous bf16 buffer (wq wk wv uk uv wo)
__global__ __launch_bounds__(256) void cast_w6(const float4* __restrict__ w0, const float4* __restrict__ w1,
                                               const float4* __restrict__ w2, const float4* __restrict__ w3,
                                               const float4* __restrict__ w4, const float4* __restrict__ w5,
                                               u16* __restrict__ Wb) {
  int i = blockIdx.x * 256 + threadIdx.x;   // < 1,572,864
  int w = i >> 18, off = i & 262143;
  const float4* s;
  switch (w) {
    case 0: s = w0; break; case 1: s = w1; break; case 2: s = w2; break;
    case 3: s = w3; break; case 4: s = w4; break; default: s = w5; break;
  }
  float4 v = s[off];
  ushort4 o; o.x = f2bf(v.x); o.y = f2bf(v.y); o.z = f2bf(v.z); o.w = f2bf(v.w);
  *(ushort4*)(Wb + ((size_t)w << 20) + (size_t)off * 4) = o;
}

// ---------------------------------------------------------------------------
// GEMM: C[m,n] = sum_k A[m,k] * B[n,k]  (m97 shape: 128x128 tile, BK=64,
// 4 waves 2x2, 4x4 16x16x32 frags/wave, swizzled global_load_lds staging)
// MODE 2: fp32 direct to Cout.
// MODE 4: self QKV  (N=3072): gn<1024 -> Q ; <2048 -> K concat ; else Vt scatter
// MODE 5: image KV  (N=2048): gn<1024 -> K rows+1024 ; else Vt cols+1024
template<int MODE>
__global__ __launch_bounds__(256) void gemm_bt(const u16* __restrict__ A, const u16* __restrict__ Bm,
                                               void* __restrict__ Cout, int M, int N, int K,
                                               u16* __restrict__ Qd, u16* __restrict__ Kd,
                                               u16* __restrict__ Vd)
{
  __shared__ __align__(16) u16 As[128 * 64];   // 16 KB
  __shared__ __align__(16) u16 Bs[128 * 64];   // 16 KB
  const int tid  = threadIdx.x;
  const int lane = tid & 63, wave = tid >> 6;
  const int wr = wave >> 1, wc = wave & 1;
  const int g = lane >> 4, c = lane & 15;
  const int bm = blockIdx.y * 128;
  const int bn = blockIdx.x * 128;

  f32x4 zf = {0.f, 0.f, 0.f, 0.f};
  f32x4 acc[4][4];
  #pragma unroll
  for (int mi = 0; mi < 4; ++mi)
    #pragma unroll
    for (int ni = 0; ni < 4; ++ni) acc[mi][ni] = zf;

  const int sr  = tid >> 3;          // 0..31
  const int pch = tid & 7;           // physical 16B chunk
  const int swz = (pch ^ (sr & 7)) * 8;  // (q*32+sr)&7 == sr&7
  const int cs  = c & 7;

  for (int k0 = 0; k0 < K; k0 += 64) {
    #pragma unroll
    for (int q = 0; q < 4; ++q)
      gl_lds16(A + (size_t)(bm + q * 32 + sr) * K + k0 + swz, &As[(q * 32 + sr) * 64 + pch * 8]);
    #pragma unroll
    for (int q = 0; q < 4; ++q)
      gl_lds16(Bm + (size_t)(bn + q * 32 + sr) * K + k0 + swz, &Bs[(q * 32 + sr) * 64 + pch * 8]);
    __syncthreads();

    #pragma unroll
    for (int ks = 0; ks < 2; ++ks) {
      bf16x8v af[4], bfr[4];
      #pragma unroll
      for (int mi = 0; mi < 4; ++mi)
        af[mi] = *(const bf16x8v*)&As[(wr * 64 + mi * 16 + c) * 64 + (((ks * 4 + g) ^ cs)) * 8];
      #pragma unroll
      for (int ni = 0; ni < 4; ++ni)
        bfr[ni] = *(const bf16x8v*)&Bs[(wc * 64 + ni * 16 + c) * 64 + (((ks * 4 + g) ^ cs)) * 8];
      #pragma unroll
      for (int mi = 0; mi < 4; ++mi)
        #pragma unroll
        for (int ni = 0; ni < 4; ++ni)
          acc[mi][ni] = __builtin_amdgcn_mfma_f32_16x16x32_bf16(af[mi], bfr[ni], acc[mi][ni], 0, 0, 0);
    }
    __syncthreads();
  }

  // epilogue: C row = 4*g + j, col = c
  #pragma unroll
  for (int mi = 0; mi < 4; ++mi) {
    #pragma unroll
    for (int ni = 0; ni < 4; ++ni) {
      #pragma unroll
      for (int j = 0; j < 4; ++j) {
        int gm = bm + wr * 64 + mi * 16 + 4 * g + j;
        int gn = bn + wc * 64 + ni * 16 + c;
        float v = acc[mi][ni][j];
        if (MODE == 2) {
          ((float*)Cout)[(size_t)gm * N + gn] = v;
        } else if (MODE == 4) {
          int b_ = gm >> 10, s_ = gm & 1023;
          if (gn < 1024)      Qd[(size_t)gm * 1024 + gn] = f2bf(v);
          else if (gn < 2048) Kd[(size_t)(b_ * 1536 + s_) * 1024 + (gn - 1024)] = f2bf(v);
          else                Vd[(size_t)(b_ * 1024 + (gn - 2048)) * 1536 + s_] = f2bf(v);
        } else if (MODE == 5) {
          int b_ = gm >> 9, s_ = gm & 511;
          if (gn < 1024) Kd[(size_t)(b_ * 1536 + 1024 + s_) * 1024 + gn] = f2bf(v);
          else           Vd[(size_t)(b_ * 1024 + (gn - 1024)) * 1536 + 1024 + s_] = f2bf(v);
        }
      }
    }
  }
}

// ---------------------------------------------------------------------------
// 6) flash attention, swapped QK^T: grid (S/64, H, B), 4 waves, 16 q/wave.
//    KVBLK=64. Each lane owns ONE q row (q=qw+c); holds S/P for k=nt*16+4g+j.
//    K tile Ks[64][64] and V tile Vs[64][64] linear + XOR-swizzle (chunk^row&7),
//    staged via global_load_lds with pre-swizzled global source.
__global__ __launch_bounds__(256) void attn_kernel(const u16* __restrict__ Q, const u16* __restrict__ Kc,
                                                   const u16* __restrict__ Vt,
                                                   const uint32_t* __restrict__ Mw,
                                                   u16* __restrict__ AO)
{
  const int b = blockIdx.z, h = blockIdx.y;
  const int q0 = blockIdx.x * 64;
  const int tid = threadIdx.x, lane = tid & 63, wave = tid >> 6;
  const int g = lane >> 4, c = lane & 15;
  const int qw = q0 + wave * 16;

  __shared__ __align__(16) u16 Ks[64 * 64];      // 8 KB
  __shared__ __align__(16) u16 Vs[64 * 64];      // 8 KB  [d][l]
  __shared__ __align__(16) u16 Ps[4][16 * 72];   // 9 KB  per-wave P, padded

  // Q fragments (B-operand): row = q = c, d-chunks 0..31 / 32..63
  bf16x8v qf0, qf1;
  {
    const u16* qp = Q + (size_t)(b * 1024 + qw + c) * 1024 + h * 64 + g * 8;
    qf0 = *(const bf16x8v*)qp;
    qf1 = *(const bf16x8v*)(qp + 32);
  }
  f32x4 zf = {0.f, 0.f, 0.f, 0.f};
  f32x4 O[4];                       // O^T frag: [d=dt*16+4g+j][q=c]
  float m = -1e9f, l = 0.f;
  #pragma unroll
  for (int dt = 0; dt < 4; ++dt) O[dt] = zf;

  const int sr  = tid >> 3;         // 0..31
  const int pch = tid & 7;
  const int swz = (pch ^ (sr & 7)) * 8;   // (sr+32)&7 == sr&7
  const int cs  = c & 7;
  const u16* Kbase = Kc + (size_t)(b * 1536) * 1024 + h * 64;
  const u16* Vbase = Vt + (size_t)(b * 1024 + h * 64) * 1536;
  const uint32_t* mrow = Mw + (size_t)(b * 1024 + qw + c) * 48;
  const float SCL = 0.18033688011112042f;  // (1/8) * log2(e)

  for (int kt = 0; kt < 24; ++kt) {
    const int l0 = kt * 64;
    gl_lds16(Kbase + (size_t)(l0 + sr) * 1024 + swz,      &Ks[sr * 64 + pch * 8]);
    gl_lds16(Kbase + (size_t)(l0 + 32 + sr) * 1024 + swz, &Ks[(32 + sr) * 64 + pch * 8]);
    gl_lds16(Vbase + (size_t)sr * 1536 + l0 + swz,        &Vs[sr * 64 + pch * 8]);
    gl_lds16(Vbase + (size_t)(32 + sr) * 1536 + l0 + swz, &Vs[(32 + sr) * 64 + pch * 8]);
    uint2 mwv = *(const uint2*)(mrow + kt * 2);
    __syncthreads();

    // S^T = K Q^T: lane (c,g) gets S[k=nt*16+4g+j][q=qw+c]
    f32x4 s[4];
    __builtin_amdgcn_s_setprio(1);
    #pragma unroll
    for (int nt = 0; nt < 4; ++nt) {
      const u16* kr = &Ks[(nt * 16 + c) * 64];
      bf16x8v k0 = *(const bf16x8v*)&kr[(g ^ cs) * 8];
      bf16x8v k1 = *(const bf16x8v*)&kr[((4 + g) ^ cs) * 8];
      f32x4 z = zf;
      z = __builtin_amdgcn_mfma_f32_16x16x32_bf16(k0, qf0, z, 0, 0, 0);
      z = __builtin_amdgcn_mfma_f32_16x16x32_bf16(k1, qf1, z, 0, 0, 0);
      s[nt] = z;
    }
    __builtin_amdgcn_s_setprio(0);

    // in-register online softmax (exp2 domain), one q-row per lane
    uint64_t mw = ((uint64_t)mwv.y << 32) | (uint64_t)mwv.x;
    float p[4][4];
    float rm = -1e9f;
    #pragma unroll
    for (int nt = 0; nt < 4; ++nt)
      #pragma unroll
      for (int j = 0; j < 4; ++j) {
        int k = nt * 16 + 4 * g + j;
        float v = s[nt][j] * SCL;
        v = ((mw >> k) & 1ull) ? v : -1e9f;
        p[nt][j] = v;
        rm = fmaxf(rm, v);
      }
    rm = fmaxf(rm, __shfl_xor(rm, 16));
    rm = fmaxf(rm, __shfl_xor(rm, 32));
    float mn = fmaxf(m, rm);
    float sc = exp2f(m - mn);
    m = mn;
    float r = 0.f;
    #pragma unroll
    for (int nt = 0; nt < 4; ++nt)
      #pragma unroll
      for (int j = 0; j < 4; ++j) {
        float e = exp2f(p[nt][j] - mn);
        p[nt][j] = e;
        r += e;
      }
    r += __shfl_xor(r, 16);
    r += __shfl_xor(r, 32);
    l = l * sc + r;
    #pragma unroll
    for (int dt = 0; dt < 4; ++dt)
      #pragma unroll
      for (int j = 0; j < 4; ++j) O[dt][j] *= sc;

    // P -> LDS [q=c][k] (pad 72), bf16-packed 8B stores
    u16* pw = &Ps[wave][0];
    #pragma unroll
    for (int nt = 0; nt < 4; ++nt) {
      uint2 pk2;
      pk2.x = cvtpk(p[nt][0], p[nt][1]);
      pk2.y = cvtpk(p[nt][2], p[nt][3]);
      *(uint2*)&pw[c * 72 + nt * 16 + g * 4] = pk2;
    }
    // PV: O^T += V-frag * P-frag
    bf16x8v pb0 = *(const bf16x8v*)&pw[c * 72 + g * 8];
    bf16x8v pb1 = *(const bf16x8v*)&pw[c * 72 + 32 + g * 8];
    __builtin_amdgcn_s_setprio(1);
    #pragma unroll
    for (int dt = 0; dt < 4; ++dt) {
      const u16* vr = &Vs[(dt * 16 + c) * 64];
      bf16x8v v0 = *(const bf16x8v*)&vr[(g ^ cs) * 8];
      bf16x8v v1 = *(const bf16x8v*)&vr[((4 + g) ^ cs) * 8];
      O[dt] = __builtin_amdgcn_mfma_f32_16x16x32_bf16(v0, pb0, O[dt], 0, 0, 0);
      O[dt] = __builtin_amdgcn_mfma_f32_16x16x32_bf16(v1, pb1, O[dt], 0, 0, 0);
    }
    __builtin_amdgcn_s_setprio(0);
    __syncthreads();
  }

  float inv = 1.f / l;
  size_t ro = (size_t)(b * 1024 + qw + c) * 1024 + h * 64;
  #pragma unroll
  for (int dt = 0; dt < 4; ++dt) {
    uint2 st;
    st.x = cvtpk(O[dt][0] * inv, O[dt][1] * inv);
    st.y = cvtpk(O[dt][2] * inv, O[dt][3] * inv);
    *(uint2*)&AO[ro + dt * 16 + 4 * g] = st;
  }
}

// ---------------------------------------------------------------------------
extern "C" void kernel_launch(void* const* d_in, const int* in_sizes, int n_in,
                              void* d_out, int out_size, void* d_ws, size_t ws_size,
                              hipStream_t stream) {
  (void)in_sizes; (void)n_in; (void)out_size; (void)ws_size;
  const float* hs = (const float*)d_in[0];
  const float* im = (const float*)d_in[1];
  const int*   mk = (const int*)d_in[2];
  const float* wq = (const float*)d_in[3];
  const float* wk = (const float*)d_in[4];
  const float* wv = (const float*)d_in[5];
  const float* uk = (const float*)d_in[6];
  const float* uv = (const float*)d_in[7];
  const float* wo = (const float*)d_in[8];

  char* ws = (char*)d_ws;
  u16* Hb  = (u16*)(ws + 0);          //  8,388,608 B  hidden bf16; reused as attn-out
  u16* Ib  = (u16*)(ws + 8388608);    //  4,194,304 B  image bf16
  u16* Wb  = (u16*)(ws + 12582912);   // 12,582,912 B  weights bf16 (wq wk wv uk uv wo)
  u16* Qb  = (u16*)(ws + 25165824);   //  8,388,608 B  Q token-major [4096][1024]
  u16* Kb  = (u16*)(ws + 33554432);   // 12,582,912 B  K concat [4][1536][1024]
  u16* Vtb = (u16*)(ws + 46137344);   // 12,582,912 B  V transposed [4][1024][1536]
  uint32_t* Mw = (uint32_t*)(ws + 58720256); // 786,432 B packed mask
  // total ws: 59,506,688 B

  mask_pack<<<24576, 256, 0, stream>>>(mk, Mw);
  cast_hi<<<6144, 256, 0, stream>>>((const float4*)hs, (const float4*)im, Hb, Ib);
  cast_w6<<<6144, 256, 0, stream>>>((const float4*)wq, (const float4*)wk, (const float4*)wv,
                                    (const float4*)uk, (const float4*)uv, (const float4*)wo, Wb);
  gemm_bt<4><<<dim3(24, 32), 256, 0, stream>>>(Hb, Wb, nullptr, 4096, 3072, 1024, Qb, Kb, Vtb);
  gemm_bt<5><<<dim3(16, 16), 256, 0, stream>>>(Ib, Wb + 3 * 1048576, nullptr, 2048, 2048, 1024,
                                               nullptr, Kb, Vtb);
  attn_kernel<<<dim3(16, 16, 4), 256, 0, stream>>>(Qb, Kb, Vtb, Mw, Hb);
  gemm_bt<2><<<dim3(8, 32), 256, 0, stream>>>(Hb, Wb + 5 * 1048576, d_out, 4096, 1024, 1024,
                                              nullptr, nullptr, nullptr);
}

// Round 3
// 186.922 us; speedup vs baseline: 1.4406x; 1.0501x over previous
//
#include <hip/hip_runtime.h>
#include <stdint.h>

// ---------------------------------------------------------------------------
// CustomGPT2MultiHeadAttention: B=4, S=1024, SI=512, D=1024, H=16, Dh=64
// Round 3: attn upgrades — T14 async reg-staging (issue-early/write-late),
// T13 defer-max (THR=8 log2-domain), scale folded into Q, XCD-grouped 1D grid
// (K/V panel pinned to one XCD L2). GEMMs unchanged from round 2.
// ---------------------------------------------------------------------------

typedef unsigned short u16;
typedef short bf16x8v __attribute__((ext_vector_type(8)));
typedef float f32x4 __attribute__((ext_vector_type(4)));

__device__ __forceinline__ u16 f2bf(float f) {
  union { float f; uint32_t u; } x; x.f = f;
  uint32_t r = x.u + 0x7FFFu + ((x.u >> 16) & 1u);   // round-to-nearest-even
  return (u16)(r >> 16);
}

// v_cvt_pk_bf16_f32: D[15:0]=bf16(a), D[31:16]=bf16(b), RNE
__device__ __forceinline__ uint32_t cvtpk(float a, float b) {
  uint32_t r;
  asm("v_cvt_pk_bf16_f32 %0, %1, %2" : "=v"(r) : "v"(a), "v"(b));
  return r;
}

__device__ __forceinline__ void gl_lds16(const u16* g, u16* l) {
  __builtin_amdgcn_global_load_lds((const __attribute__((address_space(1))) unsigned int*)g,
                                   (__attribute__((address_space(3))) unsigned int*)l,
                                   16, 0, 0);
}

// ---------------------------------------------------------------------------
// 1) mask bit-pack: 6,291,456 int32 -> 196,608 uint32 words
__global__ __launch_bounds__(256) void mask_pack(const int* __restrict__ m,
                                                 uint32_t* __restrict__ Mw) {
  int gtid = blockIdx.x * 256 + threadIdx.x;
  int lane = threadIdx.x & 63;
  unsigned long long bal = __ballot(m[gtid] != 0);
  if ((lane & 31) == 0)
    Mw[gtid >> 5] = (uint32_t)((lane == 32) ? (bal >> 32) : bal);
}

// ---------------------------------------------------------------------------
// 2) cast hidden (1,048,576 float4) + image (524,288 float4) -> bf16
__global__ __launch_bounds__(256) void cast_hi(const float4* __restrict__ hs,
                                               const float4* __restrict__ im,
                                               u16* __restrict__ Hb, u16* __restrict__ Ib) {
  int i = blockIdx.x * 256 + threadIdx.x;   // < 1,572,864
  float4 v; u16* d;
  if (i < 1048576) { v = hs[i];            d = Hb + (size_t)i * 4; }
  else             { v = im[i - 1048576];  d = Ib + (size_t)(i - 1048576) * 4; }
  ushort4 o; o.x = f2bf(v.x); o.y = f2bf(v.y); o.z = f2bf(v.z); o.w = f2bf(v.w);
  *(ushort4*)d = o;
}

// 3) cast 6 weights into one contiguous bf16 buffer (wq wk wv uk uv wo)
__global__ __launch_bounds__(256) void cast_w6(const float4* __restrict__ w0, const float4* __restrict__ w1,
                                               const float4* __restrict__ w2, const float4* __restrict__ w3,
                                               const float4* __restrict__ w4, const float4* __restrict__ w5,
                                               u16* __restrict__ Wb) {
  int i = blockIdx.x * 256 + threadIdx.x;   // < 1,572,864
  int w = i >> 18, off = i & 262143;
  const float4* s;
  switch (w) {
    case 0: s = w0; break; case 1: s = w1; break; case 2: s = w2; break;
    case 3: s = w3; break; case 4: s = w4; break; default: s = w5; break;
  }
  float4 v = s[off];
  ushort4 o; o.x = f2bf(v.x); o.y = f2bf(v.y); o.z = f2bf(v.z); o.w = f2bf(v.w);
  *(ushort4*)(Wb + ((size_t)w << 20) + (size_t)off * 4) = o;
}

// ---------------------------------------------------------------------------
// GEMM: C[m,n] = sum_k A[m,k] * B[n,k]  (m97 shape: 128x128 tile, BK=64,
// 4 waves 2x2, 4x4 16x16x32 frags/wave, swizzled global_load_lds staging)
// MODE 2: fp32 direct to Cout.
// MODE 4: self QKV  (N=3072): gn<1024 -> Q (pre-scaled by 1/8*log2e);
//                   <2048 -> K concat ; else Vt scatter
// MODE 5: image KV  (N=2048): gn<1024 -> K rows+1024 ; else Vt cols+1024
template<int MODE>
__global__ __launch_bounds__(256) void gemm_bt(const u16* __restrict__ A, const u16* __restrict__ Bm,
                                               void* __restrict__ Cout, int M, int N, int K,
                                               u16* __restrict__ Qd, u16* __restrict__ Kd,
                                               u16* __restrict__ Vd)
{
  __shared__ __align__(16) u16 As[128 * 64];   // 16 KB
  __shared__ __align__(16) u16 Bs[128 * 64];   // 16 KB
  const int tid  = threadIdx.x;
  const int lane = tid & 63, wave = tid >> 6;
  const int wr = wave >> 1, wc = wave & 1;
  const int g = lane >> 4, c = lane & 15;
  const int bm = blockIdx.y * 128;
  const int bn = blockIdx.x * 128;

  f32x4 zf = {0.f, 0.f, 0.f, 0.f};
  f32x4 acc[4][4];
  #pragma unroll
  for (int mi = 0; mi < 4; ++mi)
    #pragma unroll
    for (int ni = 0; ni < 4; ++ni) acc[mi][ni] = zf;

  const int sr  = tid >> 3;          // 0..31
  const int pch = tid & 7;           // physical 16B chunk
  const int swz = (pch ^ (sr & 7)) * 8;  // (q*32+sr)&7 == sr&7
  const int cs  = c & 7;

  for (int k0 = 0; k0 < K; k0 += 64) {
    #pragma unroll
    for (int q = 0; q < 4; ++q)
      gl_lds16(A + (size_t)(bm + q * 32 + sr) * K + k0 + swz, &As[(q * 32 + sr) * 64 + pch * 8]);
    #pragma unroll
    for (int q = 0; q < 4; ++q)
      gl_lds16(Bm + (size_t)(bn + q * 32 + sr) * K + k0 + swz, &Bs[(q * 32 + sr) * 64 + pch * 8]);
    __syncthreads();

    #pragma unroll
    for (int ks = 0; ks < 2; ++ks) {
      bf16x8v af[4], bfr[4];
      #pragma unroll
      for (int mi = 0; mi < 4; ++mi)
        af[mi] = *(const bf16x8v*)&As[(wr * 64 + mi * 16 + c) * 64 + (((ks * 4 + g) ^ cs)) * 8];
      #pragma unroll
      for (int ni = 0; ni < 4; ++ni)
        bfr[ni] = *(const bf16x8v*)&Bs[(wc * 64 + ni * 16 + c) * 64 + (((ks * 4 + g) ^ cs)) * 8];
      #pragma unroll
      for (int mi = 0; mi < 4; ++mi)
        #pragma unroll
        for (int ni = 0; ni < 4; ++ni)
          acc[mi][ni] = __builtin_amdgcn_mfma_f32_16x16x32_bf16(af[mi], bfr[ni], acc[mi][ni], 0, 0, 0);
    }
    __syncthreads();
  }

  // epilogue: C row = 4*g + j, col = c
  #pragma unroll
  for (int mi = 0; mi < 4; ++mi) {
    #pragma unroll
    for (int ni = 0; ni < 4; ++ni) {
      #pragma unroll
      for (int j = 0; j < 4; ++j) {
        int gm = bm + wr * 64 + mi * 16 + 4 * g + j;
        int gn = bn + wc * 64 + ni * 16 + c;
        float v = acc[mi][ni][j];
        if (MODE == 2) {
          ((float*)Cout)[(size_t)gm * N + gn] = v;
        } else if (MODE == 4) {
          int b_ = gm >> 10, s_ = gm & 1023;
          if (gn < 1024)      Qd[(size_t)gm * 1024 + gn] = f2bf(v * 0.18033688011112042f);
          else if (gn < 2048) Kd[(size_t)(b_ * 1536 + s_) * 1024 + (gn - 1024)] = f2bf(v);
          else                Vd[(size_t)(b_ * 1024 + (gn - 2048)) * 1536 + s_] = f2bf(v);
        } else if (MODE == 5) {
          int b_ = gm >> 9, s_ = gm & 511;
          if (gn < 1024) Kd[(size_t)(b_ * 1536 + 1024 + s_) * 1024 + gn] = f2bf(v);
          else           Vd[(size_t)(b_ * 1024 + (gn - 1024)) * 1536 + 1024 + s_] = f2bf(v);
        }
      }
    }
  }
}

// ---------------------------------------------------------------------------
// 6) flash attention, swapped QK^T: 1D grid of 1024 blocks, 4 waves, 16 q/wave.
//    KVBLK=64. Lane owns q row (qw+c); holds S/P for k=nt*16+4g+j.
//    T14: K/V global->reg issued before compute, reg->LDS (swizzled write)
//    after the read-barrier. T13: defer-max THR=8 (log2 domain).
//    XCD grouping: grp = bid & 63 -> XCD = grp % 8 (64-block stride, 64%8==0),
//    so all 16 q-tiles of one (b,h) K/V panel share one XCD L2.
__global__ __launch_bounds__(256) void attn_kernel(const u16* __restrict__ Q, const u16* __restrict__ Kc,
                                                   const u16* __restrict__ Vt,
                                                   const uint32_t* __restrict__ Mw,
                                                   u16* __restrict__ AO)
{
  const int bid = blockIdx.x;
  const int grp = bid & 63;           // (b,h) group; XCD = bid%8 = grp%8
  const int qt  = bid >> 6;
  const int h = grp & 15, b = grp >> 4;
  const int q0 = qt * 64;
  const int tid = threadIdx.x, lane = tid & 63, wave = tid >> 6;
  const int g = lane >> 4, c = lane & 15;
  const int qw = q0 + wave * 16;

  __shared__ __align__(16) u16 Ks[64 * 64];      // 8 KB
  __shared__ __align__(16) u16 Vs[64 * 64];      // 8 KB  [d][l]
  __shared__ __align__(16) u16 Ps[4][16 * 72];   // 9 KB  per-wave P, padded

  // Q fragments (B-operand): row = q = c, d-chunks 0..31 / 32..63.
  // Q is pre-scaled by (1/8)*log2(e) at the QKV-GEMM epilogue.
  bf16x8v qf0, qf1;
  {
    const u16* qp = Q + (size_t)(b * 1024 + qw + c) * 1024 + h * 64 + g * 8;
    qf0 = *(const bf16x8v*)qp;
    qf1 = *(const bf16x8v*)(qp + 32);
  }
  f32x4 zf = {0.f, 0.f, 0.f, 0.f};
  f32x4 O[4];                       // O^T frag: [d=dt*16+4g+j][q=c]
  float m = -1e9f, l = 0.f;
  #pragma unroll
  for (int dt = 0; dt < 4; ++dt) O[dt] = zf;

  const int sr  = tid >> 3;         // 0..7
  const int pch = tid & 7;
  const int swz = (pch ^ (sr & 7)) * 8;   // write-side XOR swizzle
  const int cs  = c & 7;
  const u16* Kbase = Kc + (size_t)(b * 1536) * 1024 + h * 64;
  const u16* Vbase = Vt + (size_t)(b * 1024 + h * 64) * 1536;
  const uint32_t* mrow = Mw + (size_t)(b * 1024 + qw + c) * 48;

  // prologue: stage tile 0
  bf16x8v kr0, kr1, vr0, vr1;
  kr0 = *(const bf16x8v*)(Kbase + (size_t)sr * 1024 + pch * 8);
  kr1 = *(const bf16x8v*)(Kbase + (size_t)(32 + sr) * 1024 + pch * 8);
  vr0 = *(const bf16x8v*)(Vbase + (size_t)sr * 1536 + pch * 8);
  vr1 = *(const bf16x8v*)(Vbase + (size_t)(32 + sr) * 1536 + pch * 8);
  *(bf16x8v*)&Ks[sr * 64 + swz]        = kr0;
  *(bf16x8v*)&Ks[(32 + sr) * 64 + swz] = kr1;
  *(bf16x8v*)&Vs[sr * 64 + swz]        = vr0;
  *(bf16x8v*)&Vs[(32 + sr) * 64 + swz] = vr1;
  __syncthreads();

  for (int kt = 0; kt < 24; ++kt) {
    // T14 issue-early: next tile global->reg, latency hides under compute
    if (kt < 23) {
      const int ln = (kt + 1) * 64;
      kr0 = *(const bf16x8v*)(Kbase + (size_t)(ln + sr) * 1024 + pch * 8);
      kr1 = *(const bf16x8v*)(Kbase + (size_t)(ln + 32 + sr) * 1024 + pch * 8);
      vr0 = *(const bf16x8v*)(Vbase + (size_t)sr * 1536 + ln + pch * 8);
      vr1 = *(const bf16x8v*)(Vbase + (size_t)(32 + sr) * 1536 + ln + pch * 8);
    }
    uint2 mwv = *(const uint2*)(mrow + kt * 2);

    // S^T = K Q^T: lane (c,g) gets S[k=nt*16+4g+j][q=qw+c] (already log2-scaled)
    f32x4 s[4];
    __builtin_amdgcn_s_setprio(1);
    #pragma unroll
    for (int nt = 0; nt < 4; ++nt) {
      const u16* kr = &Ks[(nt * 16 + c) * 64];
      bf16x8v k0 = *(const bf16x8v*)&kr[(g ^ cs) * 8];
      bf16x8v k1 = *(const bf16x8v*)&kr[((4 + g) ^ cs) * 8];
      f32x4 z = zf;
      z = __builtin_amdgcn_mfma_f32_16x16x32_bf16(k0, qf0, z, 0, 0, 0);
      z = __builtin_amdgcn_mfma_f32_16x16x32_bf16(k1, qf1, z, 0, 0, 0);
      s[nt] = z;
    }
    __builtin_amdgcn_s_setprio(0);

    // in-register online softmax (log2 domain), one q-row per lane
    uint64_t mq = (((uint64_t)mwv.y << 32) | (uint64_t)mwv.x) >> (4 * g);
    float rm = -1e9f;
    #pragma unroll
    for (int nt = 0; nt < 4; ++nt)
      #pragma unroll
      for (int j = 0; j < 4; ++j) {
        float v = ((mq >> (16 * nt + j)) & 1ull) ? s[nt][j] : -1e9f;
        s[nt][j] = v;
        rm = fmaxf(rm, v);
      }
    rm = fmaxf(rm, __shfl_xor(rm, 16));
    rm = fmaxf(rm, __shfl_xor(rm, 32));
    // T13 defer-max: skip rescale while max grows by < 8 (p bounded by 2^8)
    if (!__all(rm <= m + 8.0f)) {
      float mn = fmaxf(m, rm);
      float sc = exp2f(m - mn);
      m = mn;
      l *= sc;
      #pragma unroll
      for (int dt = 0; dt < 4; ++dt)
        #pragma unroll
        for (int j = 0; j < 4; ++j) O[dt][j] *= sc;
    }
    float r = 0.f;
    #pragma unroll
    for (int nt = 0; nt < 4; ++nt)
      #pragma unroll
      for (int j = 0; j < 4; ++j) {
        float e = exp2f(s[nt][j] - m);
        s[nt][j] = e;
        r += e;
      }
    r += __shfl_xor(r, 16);
    r += __shfl_xor(r, 32);
    l += r;

    // P -> LDS [q=c][k] (pad 72), bf16-packed 8B stores
    u16* pw = &Ps[wave][0];
    #pragma unroll
    for (int nt = 0; nt < 4; ++nt) {
      uint2 pk2;
      pk2.x = cvtpk(s[nt][0], s[nt][1]);
      pk2.y = cvtpk(s[nt][2], s[nt][3]);
      *(uint2*)&pw[c * 72 + nt * 16 + g * 4] = pk2;
    }
    // PV: O^T += V-frag * P-frag
    bf16x8v pb0 = *(const bf16x8v*)&pw[c * 72 + g * 8];
    bf16x8v pb1 = *(const bf16x8v*)&pw[c * 72 + 32 + g * 8];
    __builtin_amdgcn_s_setprio(1);
    #pragma unroll
    for (int dt = 0; dt < 4; ++dt) {
      const u16* vr = &Vs[(dt * 16 + c) * 64];
      bf16x8v v0 = *(const bf16x8v*)&vr[(g ^ cs) * 8];
      bf16x8v v1 = *(const bf16x8v*)&vr[((4 + g) ^ cs) * 8];
      O[dt] = __builtin_amdgcn_mfma_f32_16x16x32_bf16(v0, pb0, O[dt], 0, 0, 0);
      O[dt] = __builtin_amdgcn_mfma_f32_16x16x32_bf16(v1, pb1, O[dt], 0, 0, 0);
    }
    __builtin_amdgcn_s_setprio(0);

    __syncthreads();                 // all waves done READING Ks/Vs
    if (kt < 23) {
      // T14 write-late: regs -> LDS (swizzled dest), then release
      *(bf16x8v*)&Ks[sr * 64 + swz]        = kr0;
      *(bf16x8v*)&Ks[(32 + sr) * 64 + swz] = kr1;
      *(bf16x8v*)&Vs[sr * 64 + swz]        = vr0;
      *(bf16x8v*)&Vs[(32 + sr) * 64 + swz] = vr1;
      __syncthreads();
    }
  }

  float inv = 1.f / l;
  size_t ro = (size_t)(b * 1024 + qw + c) * 1024 + h * 64;
  #pragma unroll
  for (int dt = 0; dt < 4; ++dt) {
    uint2 st;
    st.x = cvtpk(O[dt][0] * inv, O[dt][1] * inv);
    st.y = cvtpk(O[dt][2] * inv, O[dt][3] * inv);
    *(uint2*)&AO[ro + dt * 16 + 4 * g] = st;
  }
}

// ---------------------------------------------------------------------------
extern "C" void kernel_launch(void* const* d_in, const int* in_sizes, int n_in,
                              void* d_out, int out_size, void* d_ws, size_t ws_size,
                              hipStream_t stream) {
  (void)in_sizes; (void)n_in; (void)out_size; (void)ws_size;
  const float* hs = (const float*)d_in[0];
  const float* im = (const float*)d_in[1];
  const int*   mk = (const int*)d_in[2];
  const float* wq = (const float*)d_in[3];
  const float* wk = (const float*)d_in[4];
  const float* wv = (const float*)d_in[5];
  const float* uk = (const float*)d_in[6];
  const float* uv = (const float*)d_in[7];
  const float* wo = (const float*)d_in[8];

  char* ws = (char*)d_ws;
  u16* Hb  = (u16*)(ws + 0);          //  8,388,608 B  hidden bf16; reused as attn-out
  u16* Ib  = (u16*)(ws + 8388608);    //  4,194,304 B  image bf16
  u16* Wb  = (u16*)(ws + 12582912);   // 12,582,912 B  weights bf16 (wq wk wv uk uv wo)
  u16* Qb  = (u16*)(ws + 25165824);   //  8,388,608 B  Q token-major [4096][1024] (pre-scaled)
  u16* Kb  = (u16*)(ws + 33554432);   // 12,582,912 B  K concat [4][1536][1024]
  u16* Vtb = (u16*)(ws + 46137344);   // 12,582,912 B  V transposed [4][1024][1536]
  uint32_t* Mw = (uint32_t*)(ws + 58720256); // 786,432 B packed mask
  // total ws: 59,506,688 B

  mask_pack<<<24576, 256, 0, stream>>>(mk, Mw);
  cast_hi<<<6144, 256, 0, stream>>>((const float4*)hs, (const float4*)im, Hb, Ib);
  cast_w6<<<6144, 256, 0, stream>>>((const float4*)wq, (const float4*)wk, (const float4*)wv,
                                    (const float4*)uk, (const float4*)uv, (const float4*)wo, Wb);
  gemm_bt<4><<<dim3(24, 32), 256, 0, stream>>>(Hb, Wb, nullptr, 4096, 3072, 1024, Qb, Kb, Vtb);
  gemm_bt<5><<<dim3(16, 16), 256, 0, stream>>>(Ib, Wb + 3 * 1048576, nullptr, 2048, 2048, 1024,
                                               nullptr, Kb, Vtb);
  attn_kernel<<<1024, 256, 0, stream>>>(Qb, Kb, Vtb, Mw, Hb);
  gemm_bt<2><<<dim3(8, 32), 256, 0, stream>>>(Hb, Wb + 5 * 1048576, d_out, 4096, 1024, 1024,
                                              nullptr, nullptr, nullptr);
}

// Round 4
// 169.788 us; speedup vs baseline: 1.5860x; 1.1009x over previous
//
#include <hip/hip_runtime.h>
#include <stdint.h>

// ---------------------------------------------------------------------------
// CustomGPT2MultiHeadAttention: B=4, S=1024, SI=512, D=1024, H=16, Dh=64
// Round 4: attn softmax rewritten max-free (bounded log2-domain scores ->
// unnormalized exp2, bit-AND masking, epilogue-only reduction); prep kernels
// fused into one; gemm<4>+gemm<5> fused into one 1024-block dispatch.
// ---------------------------------------------------------------------------

typedef unsigned short u16;
typedef short bf16x8v __attribute__((ext_vector_type(8)));
typedef float f32x4 __attribute__((ext_vector_type(4)));

__device__ __forceinline__ u16 f2bf(float f) {
  union { float f; uint32_t u; } x; x.f = f;
  uint32_t r = x.u + 0x7FFFu + ((x.u >> 16) & 1u);   // round-to-nearest-even
  return (u16)(r >> 16);
}

// v_cvt_pk_bf16_f32: D[15:0]=bf16(a), D[31:16]=bf16(b), RNE
__device__ __forceinline__ uint32_t cvtpk(float a, float b) {
  uint32_t r;
  asm("v_cvt_pk_bf16_f32 %0, %1, %2" : "=v"(r) : "v"(a), "v"(b));
  return r;
}

// p = bit(msrc,off) ? e : 0   via sign-extended 1-bit field + AND (2 VALU)
__device__ __forceinline__ float maskand(float e, uint32_t msrc, int off) {
  uint32_t mm = (uint32_t)((int32_t)(msrc << (31 - off)) >> 31);
  union { float f; uint32_t u; } x; x.f = e; x.u &= mm; return x.f;
}

__device__ __forceinline__ void gl_lds16(const u16* g, u16* l) {
  __builtin_amdgcn_global_load_lds((const __attribute__((address_space(1))) unsigned int*)g,
                                   (__attribute__((address_space(3))) unsigned int*)l,
                                   16, 0, 0);
}

// ---------------------------------------------------------------------------
// 1) fused prep: mask bit-pack + hidden/image cast + 6-weight cast.
//    grid-stride, 2048 blocks x 256.
__global__ __launch_bounds__(256) void prep(const int* __restrict__ mk,
                                            const float4* __restrict__ hs,
                                            const float4* __restrict__ im,
                                            const float4* __restrict__ w0, const float4* __restrict__ w1,
                                            const float4* __restrict__ w2, const float4* __restrict__ w3,
                                            const float4* __restrict__ w4, const float4* __restrict__ w5,
                                            uint32_t* __restrict__ Mw,
                                            u16* __restrict__ Hb, u16* __restrict__ Ib,
                                            u16* __restrict__ Wb) {
  const int nthr = gridDim.x * 256;
  const int gid = blockIdx.x * 256 + threadIdx.x;

  // mask: 196,608 words, 32 ints -> 1 u32 each (bit i of word w = mk[32w+i]!=0)
  for (int w = gid; w < 196608; w += nthr) {
    const int4* p = (const int4*)(mk + (size_t)w * 32);
    uint32_t bits = 0;
    #pragma unroll
    for (int c = 0; c < 8; ++c) {
      int4 v = p[c];
      bits |= (uint32_t)(v.x != 0) << (4 * c);
      bits |= (uint32_t)(v.y != 0) << (4 * c + 1);
      bits |= (uint32_t)(v.z != 0) << (4 * c + 2);
      bits |= (uint32_t)(v.w != 0) << (4 * c + 3);
    }
    Mw[w] = bits;
  }
  // hidden (1,048,576 f4) + image (524,288 f4)
  for (int i = gid; i < 1572864; i += nthr) {
    float4 v; u16* d;
    if (i < 1048576) { v = hs[i];            d = Hb + (size_t)i * 4; }
    else             { v = im[i - 1048576];  d = Ib + (size_t)(i - 1048576) * 4; }
    ushort4 o; o.x = f2bf(v.x); o.y = f2bf(v.y); o.z = f2bf(v.z); o.w = f2bf(v.w);
    *(ushort4*)d = o;
  }
  // weights: 6 x 262,144 f4 -> contiguous bf16 (wq wk wv uk uv wo)
  for (int i = gid; i < 1572864; i += nthr) {
    int w = i >> 18, off = i & 262143;
    const float4* s;
    switch (w) {
      case 0: s = w0; break; case 1: s = w1; break; case 2: s = w2; break;
      case 3: s = w3; break; case 4: s = w4; break; default: s = w5; break;
    }
    float4 v = s[off];
    ushort4 o; o.x = f2bf(v.x); o.y = f2bf(v.y); o.z = f2bf(v.z); o.w = f2bf(v.w);
    *(ushort4*)(Wb + ((size_t)w << 20) + (size_t)off * 4) = o;
  }
}

// ---------------------------------------------------------------------------
// GEMM core body (m97 shape: 128x128 tile, BK=64, 4 waves 2x2, 4x4 frags,
// swizzled global_load_lds staging), K=1024 fixed.
// Fused QKV dispatch: blocks 0..767 = self (mode 4), 768..1023 = image (mode 5).
__global__ __launch_bounds__(256) void gemm_qkv(const u16* __restrict__ Hb, const u16* __restrict__ Ib,
                                                const u16* __restrict__ Wb,
                                                u16* __restrict__ Qd, u16* __restrict__ Kd,
                                                u16* __restrict__ Vd)
{
  __shared__ __align__(16) u16 As[128 * 64];   // 16 KB
  __shared__ __align__(16) u16 Bs[128 * 64];   // 16 KB
  const int bid = blockIdx.x;
  const u16 *A, *Bm;
  int bm, bn, mode;
  if (bid < 768) { mode = 4; A = Hb; Bm = Wb;
                   int y = bid / 24; bm = y * 128; bn = (bid - y * 24) * 128; }
  else           { mode = 5; A = Ib; Bm = Wb + 3 * 1048576;
                   int r = bid - 768; bm = (r >> 4) * 128; bn = (r & 15) * 128; }
  const int tid  = threadIdx.x;
  const int lane = tid & 63, wave = tid >> 6;
  const int wr = wave >> 1, wc = wave & 1;
  const int g = lane >> 4, c = lane & 15;

  f32x4 zf = {0.f, 0.f, 0.f, 0.f};
  f32x4 acc[4][4];
  #pragma unroll
  for (int mi = 0; mi < 4; ++mi)
    #pragma unroll
    for (int ni = 0; ni < 4; ++ni) acc[mi][ni] = zf;

  const int sr  = tid >> 3;          // 0..31
  const int pch = tid & 7;           // physical 16B chunk
  const int swz = (pch ^ (sr & 7)) * 8;
  const int cs  = c & 15 & 7;

  for (int k0 = 0; k0 < 1024; k0 += 64) {
    #pragma unroll
    for (int q = 0; q < 4; ++q)
      gl_lds16(A + (size_t)(bm + q * 32 + sr) * 1024 + k0 + swz, &As[(q * 32 + sr) * 64 + pch * 8]);
    #pragma unroll
    for (int q = 0; q < 4; ++q)
      gl_lds16(Bm + (size_t)(bn + q * 32 + sr) * 1024 + k0 + swz, &Bs[(q * 32 + sr) * 64 + pch * 8]);
    __syncthreads();

    #pragma unroll
    for (int ks = 0; ks < 2; ++ks) {
      bf16x8v af[4], bfr[4];
      #pragma unroll
      for (int mi = 0; mi < 4; ++mi)
        af[mi] = *(const bf16x8v*)&As[(wr * 64 + mi * 16 + c) * 64 + (((ks * 4 + g) ^ cs)) * 8];
      #pragma unroll
      for (int ni = 0; ni < 4; ++ni)
        bfr[ni] = *(const bf16x8v*)&Bs[(wc * 64 + ni * 16 + c) * 64 + (((ks * 4 + g) ^ cs)) * 8];
      #pragma unroll
      for (int mi = 0; mi < 4; ++mi)
        #pragma unroll
        for (int ni = 0; ni < 4; ++ni)
          acc[mi][ni] = __builtin_amdgcn_mfma_f32_16x16x32_bf16(af[mi], bfr[ni], acc[mi][ni], 0, 0, 0);
    }
    __syncthreads();
  }

  // epilogue: C row = 4*g + j, col = c
  #pragma unroll
  for (int mi = 0; mi < 4; ++mi) {
    #pragma unroll
    for (int ni = 0; ni < 4; ++ni) {
      #pragma unroll
      for (int j = 0; j < 4; ++j) {
        int gm = bm + wr * 64 + mi * 16 + 4 * g + j;
        int gn = bn + wc * 64 + ni * 16 + c;
        float v = acc[mi][ni][j];
        if (mode == 4) {
          int b_ = gm >> 10, s_ = gm & 1023;
          if (gn < 1024)      Qd[(size_t)gm * 1024 + gn] = f2bf(v * 0.18033688011112042f);
          else if (gn < 2048) Kd[(size_t)(b_ * 1536 + s_) * 1024 + (gn - 1024)] = f2bf(v);
          else                Vd[(size_t)(b_ * 1024 + (gn - 2048)) * 1536 + s_] = f2bf(v);
        } else {
          int b_ = gm >> 9, s_ = gm & 511;
          if (gn < 1024) Kd[(size_t)(b_ * 1536 + 1024 + s_) * 1024 + gn] = f2bf(v);
          else           Vd[(size_t)(b_ * 1024 + (gn - 1024)) * 1536 + 1024 + s_] = f2bf(v);
        }
      }
    }
  }
}

// out-proj GEMM: C[m,n] = sum_k A[m,k]*B[n,k], fp32 out, M=4096 N=1024 K=1024
__global__ __launch_bounds__(256) void gemm_out(const u16* __restrict__ A, const u16* __restrict__ Bm,
                                                float* __restrict__ Cout)
{
  __shared__ __align__(16) u16 As[128 * 64];
  __shared__ __align__(16) u16 Bs[128 * 64];
  const int tid  = threadIdx.x;
  const int lane = tid & 63, wave = tid >> 6;
  const int wr = wave >> 1, wc = wave & 1;
  const int g = lane >> 4, c = lane & 15;
  const int bm = blockIdx.y * 128;
  const int bn = blockIdx.x * 128;

  f32x4 zf = {0.f, 0.f, 0.f, 0.f};
  f32x4 acc[4][4];
  #pragma unroll
  for (int mi = 0; mi < 4; ++mi)
    #pragma unroll
    for (int ni = 0; ni < 4; ++ni) acc[mi][ni] = zf;

  const int sr  = tid >> 3;
  const int pch = tid & 7;
  const int swz = (pch ^ (sr & 7)) * 8;
  const int cs  = c & 7;

  for (int k0 = 0; k0 < 1024; k0 += 64) {
    #pragma unroll
    for (int q = 0; q < 4; ++q)
      gl_lds16(A + (size_t)(bm + q * 32 + sr) * 1024 + k0 + swz, &As[(q * 32 + sr) * 64 + pch * 8]);
    #pragma unroll
    for (int q = 0; q < 4; ++q)
      gl_lds16(Bm + (size_t)(bn + q * 32 + sr) * 1024 + k0 + swz, &Bs[(q * 32 + sr) * 64 + pch * 8]);
    __syncthreads();

    #pragma unroll
    for (int ks = 0; ks < 2; ++ks) {
      bf16x8v af[4], bfr[4];
      #pragma unroll
      for (int mi = 0; mi < 4; ++mi)
        af[mi] = *(const bf16x8v*)&As[(wr * 64 + mi * 16 + c) * 64 + (((ks * 4 + g) ^ cs)) * 8];
      #pragma unroll
      for (int ni = 0; ni < 4; ++ni)
        bfr[ni] = *(const bf16x8v*)&Bs[(wc * 64 + ni * 16 + c) * 64 + (((ks * 4 + g) ^ cs)) * 8];
      #pragma unroll
      for (int mi = 0; mi < 4; ++mi)
        #pragma unroll
        for (int ni = 0; ni < 4; ++ni)
          acc[mi][ni] = __builtin_amdgcn_mfma_f32_16x16x32_bf16(af[mi], bfr[ni], acc[mi][ni], 0, 0, 0);
    }
    __syncthreads();
  }

  #pragma unroll
  for (int mi = 0; mi < 4; ++mi)
    #pragma unroll
    for (int ni = 0; ni < 4; ++ni)
      #pragma unroll
      for (int j = 0; j < 4; ++j) {
        int gm = bm + wr * 64 + mi * 16 + 4 * g + j;
        int gn = bn + wc * 64 + ni * 16 + c;
        Cout[(size_t)gm * 1024 + gn] = acc[mi][ni][j];
      }
}

// ---------------------------------------------------------------------------
// flash attention, swapped QK^T, MAX-FREE softmax (scores bounded in log2
// domain -> unnormalized p=exp2(s), bit-AND masking, epilogue-only reduce).
// 1D grid 1024 blocks (XCD-grouped: grp = bid & 63), 4 waves, 16 q/wave.
__global__ __launch_bounds__(256) void attn_kernel(const u16* __restrict__ Q, const u16* __restrict__ Kc,
                                                   const u16* __restrict__ Vt,
                                                   const uint32_t* __restrict__ Mw,
                                                   u16* __restrict__ AO)
{
  const int bid = blockIdx.x;
  const int grp = bid & 63;           // (b,h) group; XCD = bid%8 = grp%8
  const int qt  = bid >> 6;
  const int h = grp & 15, b = grp >> 4;
  const int q0 = qt * 64;
  const int tid = threadIdx.x, lane = tid & 63, wave = tid >> 6;
  const int g = lane >> 4, c = lane & 15;
  const int qw = q0 + wave * 16;

  __shared__ __align__(16) u16 Ks[64 * 64];      // 8 KB
  __shared__ __align__(16) u16 Vs[64 * 64];      // 8 KB  [d][l]
  __shared__ __align__(16) u16 Ps[4][16 * 72];   // 9 KB  per-wave P, padded

  // Q fragments (B-operand), pre-scaled by (1/8)*log2(e) at the QKV epilogue
  bf16x8v qf0, qf1;
  {
    const u16* qp = Q + (size_t)(b * 1024 + qw + c) * 1024 + h * 64 + g * 8;
    qf0 = *(const bf16x8v*)qp;
    qf1 = *(const bf16x8v*)(qp + 32);
  }
  f32x4 zf = {0.f, 0.f, 0.f, 0.f};
  f32x4 O[4];                       // O^T frag: [d=dt*16+4g+j][q=c]
  float l = 0.f;                    // per-lane partial denominator
  #pragma unroll
  for (int dt = 0; dt < 4; ++dt) O[dt] = zf;

  const int sr  = tid >> 3;         // 0..31
  const int pch = tid & 7;
  const int swz = (pch ^ (sr & 7)) * 8;   // write-side XOR swizzle
  const int cs  = c & 7;
  const u16* Kbase = Kc + (size_t)(b * 1536) * 1024 + h * 64;
  const u16* Vbase = Vt + (size_t)(b * 1024 + h * 64) * 1536;
  const uint32_t* mrow = Mw + (size_t)(b * 1024 + qw + c) * 48;

  // prologue: stage tile 0
  bf16x8v kr0, kr1, vr0, vr1;
  kr0 = *(const bf16x8v*)(Kbase + (size_t)sr * 1024 + pch * 8);
  kr1 = *(const bf16x8v*)(Kbase + (size_t)(32 + sr) * 1024 + pch * 8);
  vr0 = *(const bf16x8v*)(Vbase + (size_t)sr * 1536 + pch * 8);
  vr1 = *(const bf16x8v*)(Vbase + (size_t)(32 + sr) * 1536 + pch * 8);
  *(bf16x8v*)&Ks[sr * 64 + swz]        = kr0;
  *(bf16x8v*)&Ks[(32 + sr) * 64 + swz] = kr1;
  *(bf16x8v*)&Vs[sr * 64 + swz]        = vr0;
  *(bf16x8v*)&Vs[(32 + sr) * 64 + swz] = vr1;
  __syncthreads();

  for (int kt = 0; kt < 24; ++kt) {
    // T14 issue-early: next tile global->reg, latency hides under compute
    if (kt < 23) {
      const int ln = (kt + 1) * 64;
      kr0 = *(const bf16x8v*)(Kbase + (size_t)(ln + sr) * 1024 + pch * 8);
      kr1 = *(const bf16x8v*)(Kbase + (size_t)(ln + 32 + sr) * 1024 + pch * 8);
      vr0 = *(const bf16x8v*)(Vbase + (size_t)sr * 1536 + ln + pch * 8);
      vr1 = *(const bf16x8v*)(Vbase + (size_t)(32 + sr) * 1536 + ln + pch * 8);
    }
    uint2 mwv = *(const uint2*)(mrow + kt * 2);

    // S^T = K Q^T: lane (c,g) gets S[k=nt*16+4g+j][q=qw+c] (log2-scaled)
    f32x4 s[4];
    __builtin_amdgcn_s_setprio(1);
    #pragma unroll
    for (int nt = 0; nt < 4; ++nt) {
      const u16* kr = &Ks[(nt * 16 + c) * 64];
      bf16x8v k0 = *(const bf16x8v*)&kr[(g ^ cs) * 8];
      bf16x8v k1 = *(const bf16x8v*)&kr[((4 + g) ^ cs) * 8];
      f32x4 z = zf;
      z = __builtin_amdgcn_mfma_f32_16x16x32_bf16(k0, qf0, z, 0, 0, 0);
      z = __builtin_amdgcn_mfma_f32_16x16x32_bf16(k1, qf1, z, 0, 0, 0);
      s[nt] = z;
    }
    __builtin_amdgcn_s_setprio(0);

    // max-free softmax: p = exp2(s) & sext(maskbit); l += p  (no shuffles)
    uint64_t mq = (((uint64_t)mwv.y << 32) | (uint64_t)mwv.x) >> (4 * g);
    uint32_t mlo = (uint32_t)mq, mhi = (uint32_t)(mq >> 32);
    #pragma unroll
    for (int nt = 0; nt < 4; ++nt) {
      uint32_t msrc = (nt < 2) ? mlo : mhi;
      #pragma unroll
      for (int j = 0; j < 4; ++j) {
        float e = exp2f(s[nt][j]);
        float p = maskand(e, msrc, 16 * (nt & 1) + j);
        s[nt][j] = p;
        l += p;
      }
    }

    // P -> LDS [q=c][k] (pad 72), bf16-packed 8B stores
    u16* pw = &Ps[wave][0];
    #pragma unroll
    for (int nt = 0; nt < 4; ++nt) {
      uint2 pk2;
      pk2.x = cvtpk(s[nt][0], s[nt][1]);
      pk2.y = cvtpk(s[nt][2], s[nt][3]);
      *(uint2*)&pw[c * 72 + nt * 16 + g * 4] = pk2;
    }
    // PV: O^T += V-frag * P-frag
    bf16x8v pb0 = *(const bf16x8v*)&pw[c * 72 + g * 8];
    bf16x8v pb1 = *(const bf16x8v*)&pw[c * 72 + 32 + g * 8];
    __builtin_amdgcn_s_setprio(1);
    #pragma unroll
    for (int dt = 0; dt < 4; ++dt) {
      const u16* vr = &Vs[(dt * 16 + c) * 64];
      bf16x8v v0 = *(const bf16x8v*)&vr[(g ^ cs) * 8];
      bf16x8v v1 = *(const bf16x8v*)&vr[((4 + g) ^ cs) * 8];
      O[dt] = __builtin_amdgcn_mfma_f32_16x16x32_bf16(v0, pb0, O[dt], 0, 0, 0);
      O[dt] = __builtin_amdgcn_mfma_f32_16x16x32_bf16(v1, pb1, O[dt], 0, 0, 0);
    }
    __builtin_amdgcn_s_setprio(0);

    __syncthreads();                 // all waves done READING Ks/Vs
    if (kt < 23) {
      *(bf16x8v*)&Ks[sr * 64 + swz]        = kr0;
      *(bf16x8v*)&Ks[(32 + sr) * 64 + swz] = kr1;
      *(bf16x8v*)&Vs[sr * 64 + swz]        = vr0;
      *(bf16x8v*)&Vs[(32 + sr) * 64 + swz] = vr1;
      __syncthreads();
    }
  }

  // epilogue: cross-g denominator reduce (only cross-lane ops in the kernel)
  float r = l;
  r += __shfl_xor(r, 16);
  r += __shfl_xor(r, 32);
  float inv = 1.f / r;
  size_t ro = (size_t)(b * 1024 + qw + c) * 1024 + h * 64;
  #pragma unroll
  for (int dt = 0; dt < 4; ++dt) {
    uint2 st;
    st.x = cvtpk(O[dt][0] * inv, O[dt][1] * inv);
    st.y = cvtpk(O[dt][2] * inv, O[dt][3] * inv);
    *(uint2*)&AO[ro + dt * 16 + 4 * g] = st;
  }
}

// ---------------------------------------------------------------------------
extern "C" void kernel_launch(void* const* d_in, const int* in_sizes, int n_in,
                              void* d_out, int out_size, void* d_ws, size_t ws_size,
                              hipStream_t stream) {
  (void)in_sizes; (void)n_in; (void)out_size; (void)ws_size;
  const float* hs = (const float*)d_in[0];
  const float* im = (const float*)d_in[1];
  const int*   mk = (const int*)d_in[2];
  const float* wq = (const float*)d_in[3];
  const float* wk = (const float*)d_in[4];
  const float* wv = (const float*)d_in[5];
  const float* uk = (const float*)d_in[6];
  const float* uv = (const float*)d_in[7];
  const float* wo = (const float*)d_in[8];

  char* ws = (char*)d_ws;
  u16* Hb  = (u16*)(ws + 0);          //  8,388,608 B  hidden bf16; reused as attn-out
  u16* Ib  = (u16*)(ws + 8388608);    //  4,194,304 B  image bf16
  u16* Wb  = (u16*)(ws + 12582912);   // 12,582,912 B  weights bf16 (wq wk wv uk uv wo)
  u16* Qb  = (u16*)(ws + 25165824);   //  8,388,608 B  Q token-major [4096][1024] (pre-scaled)
  u16* Kb  = (u16*)(ws + 33554432);   // 12,582,912 B  K concat [4][1536][1024]
  u16* Vtb = (u16*)(ws + 46137344);   // 12,582,912 B  V transposed [4][1024][1536]
  uint32_t* Mw = (uint32_t*)(ws + 58720256); // 786,432 B packed mask
  // total ws: 59,506,688 B

  prep<<<2048, 256, 0, stream>>>(mk, (const float4*)hs, (const float4*)im,
                                 (const float4*)wq, (const float4*)wk, (const float4*)wv,
                                 (const float4*)uk, (const float4*)uv, (const float4*)wo,
                                 Mw, Hb, Ib, Wb);
  gemm_qkv<<<1024, 256, 0, stream>>>(Hb, Ib, Wb, Qb, Kb, Vtb);
  attn_kernel<<<1024, 256, 0, stream>>>(Qb, Kb, Vtb, Mw, Hb);
  gemm_out<<<dim3(8, 32), 256, 0, stream>>>(Hb, Wb + 5 * 1048576, (float*)d_out);
}